// Round 11
// baseline (36693.240 us; speedup 1.0000x reference)
//
#include <hip/hip_runtime.h>
#include <hip/hip_bf16.h>
#include <math.h>

// Problem dims: B=256, K(beams)=128, H=512, D=64, DEPTH=16
#define NB    256
#define NK    128
#define NH    512
#define ND    64
#define NDEPTH 16
#define BKROWS (NB*NK)          // 32768
#define TEMPD 20.0

typedef double d4 __attribute__((ext_vector_type(4)));

// ---------------- init
__global__ void k_init(const float* __restrict__ root, float* __restrict__ states,
                       double* __restrict__ scores, unsigned char* __restrict__ hist) {
    int idx = blockIdx.x * 256 + threadIdx.x;          // 0 .. 16,777,215
    states[idx] = root[idx & (NH - 1)];
    if (idx < BKROWS) scores[idx] = ((idx & (NK - 1)) == 0) ? 0.0 : -1e9;
    if (idx < BKROWS * NDEPTH) hist[idx] = 0;
}

// ---------------- K1: f64 MFMA logits GEMM + log-softmax + cand = score + logp
// grid 512, 256 threads = 4 waves. Block 64 rows x 64 cols; wave wv: rows wv*16..+15.
// (round-9 form, measured best; T14 variant regressed)
__global__ void __launch_bounds__(256, 4)
k_logits(const float* __restrict__ states,
         const float* __restrict__ Wl,      // [H][D] f32 row-major
         const float* __restrict__ bl,      // [D]
         const double* __restrict__ scores, // [B*K]
         double* __restrict__ cand)         // [B*K][D]
{
    __shared__ double wl[16][64];    // [kk][col] -- B-reads stride-1
    __shared__ double stT[16][67];   // [kk][r]   -- A-reads stride-1
    const int rowb = blockIdx.x * 64;
    const int t    = threadIdx.x;
    const int lane = t & 63;
    const int wv   = t >> 6;
    const int li   = lane & 15;
    const int kq   = lane >> 4;

    d4 acc[4];
    #pragma unroll
    for (int c = 0; c < 4; ++c) { acc[c][0]=0.0; acc[c][1]=0.0; acc[c][2]=0.0; acc[c][3]=0.0; }

    for (int kc = 0; kc < NH; kc += 16) {
        // W tile: 512 double2 (from f32), linear b128 writes
        #pragma unroll
        for (int j = 0; j < 2; ++j) {
            int idx = j * 256 + t;
            int row = idx >> 5, cp = idx & 31;
            float2 v = *(const float2*)&Wl[(size_t)(kc + row) * ND + 2 * cp];
            double2 d; d.x = (double)v.x; d.y = (double)v.y;
            *(double2*)&wl[row][2 * cp] = d;
        }
        // S tile transposed: stT[kk][r] = S[rowb+r][kc+kk]
        #pragma unroll
        for (int j = 0; j < 2; ++j) {
            int idx = j * 256 + t;
            int r = idx >> 3, cp = idx & 7;
            float2 v = *(const float2*)&states[(size_t)(rowb + r) * NH + kc + 2 * cp];
            stT[2 * cp][r]     = (double)v.x;
            stT[2 * cp + 1][r] = (double)v.y;
        }
        __syncthreads();

        #pragma unroll
        for (int ks = 0; ks < 4; ++ks) {
            int kk = 4 * ks + kq;
            double a  = stT[kk][wv * 16 + li];
            double b0 = wl[kk][     li];
            double b1 = wl[kk][16 + li];
            double b2 = wl[kk][32 + li];
            double b3 = wl[kk][48 + li];
            acc[0] = __builtin_amdgcn_mfma_f64_16x16x4f64(a, b0, acc[0], 0, 0, 0);
            acc[1] = __builtin_amdgcn_mfma_f64_16x16x4f64(a, b1, acc[1], 0, 0, 0);
            acc[2] = __builtin_amdgcn_mfma_f64_16x16x4f64(a, b2, acc[2], 0, 0, 0);
            acc[3] = __builtin_amdgcn_mfma_f64_16x16x4f64(a, b3, acc[3], 0, 0, 0);
        }
        __syncthreads();
    }

    const double bd0 = (double)bl[li];
    const double bd1 = (double)bl[16 + li];
    const double bd2 = (double)bl[32 + li];
    const double bd3 = (double)bl[48 + li];
    #pragma unroll
    for (int n = 0; n < 4; ++n) {
        int row = rowb + wv * 16 + kq + 4 * n;
        double x0 = (acc[0][n] + bd0) / TEMPD;
        double x1 = (acc[1][n] + bd1) / TEMPD;
        double x2 = (acc[2][n] + bd2) / TEMPD;
        double x3 = (acc[3][n] + bd3) / TEMPD;
        double m = fmax(fmax(x0, x1), fmax(x2, x3));
        #pragma unroll
        for (int off = 1; off <= 8; off <<= 1) m = fmax(m, __shfl_xor(m, off, 64));
        double e = exp(x0 - m) + exp(x1 - m) + exp(x2 - m) + exp(x3 - m);
        #pragma unroll
        for (int off = 1; off <= 8; off <<= 1) e += __shfl_xor(e, off, 64);
        double ls = log(e);
        double sc = scores[row];
        cand[(size_t)row * ND +      li] = sc + x0 - m - ls;
        cand[(size_t)row * ND + 16 + li] = sc + x1 - m - ls;
        cand[(size_t)row * ND + 32 + li] = sc + x2 - m - ls;
        cand[(size_t)row * ND + 48 + li] = sc + x3 - m - ls;
    }
}

// ---------------- K2: per-batch top-128 of 8192 (value desc, index asc) + hist gather
// Single-wave selection from LDS; zero barriers inside the 128-iteration loop.
__global__ void __launch_bounds__(256)
k_topk(const double* __restrict__ cand,    // [B][8192]
       double* __restrict__ scores,
       int* __restrict__ parent, int* __restrict__ decs,
       const unsigned char* __restrict__ hist_in,
       unsigned char* __restrict__ hist_out,
       int tstep)
{
    extern __shared__ double smem[];
    double* L  = smem;                       // [128][65] flattened
    int*    sp = (int*)(smem + 128 * 65);    // [128]
    int*    sd = sp + NK;                    // [128]

    const int b = blockIdx.x;
    const int t = threadIdx.x;
    const double* cb = cand + (size_t)b * (NK * ND);

    #pragma unroll
    for (int j = 0; j < 32; ++j) {
        int i = j * 256 + t;
        L[(i >> 6) * 65 + (i & 63)] = cb[i];
    }
    __syncthreads();

    if (t < 64) {                            // wave 0 only; wave-synchronous
        const int lane = t;
        double mv = L[lane]; int mi = lane;
        for (int i = 1; i < 128; ++i) {
            double v = L[i * 65 + lane];
            if (v > mv) { mv = v; mi = i * 64 + lane; }
        }
        for (int it = 0; it < NK; ++it) {
            double m = mv; int idx = mi;
            #pragma unroll
            for (int off = 1; off <= 32; off <<= 1) {
                double m2 = __shfl_xor(m, off, 64);
                int    i2 = __shfl_xor(idx, off, 64);
                if (m2 > m || (m2 == m && i2 < idx)) { m = m2; idx = i2; }
            }
            const int wrow = idx >> 6, wcol = idx & 63;
            if (lane == 0) {
                scores[b * NK + it] = m;
                parent[b * NK + it] = wrow;
                decs  [b * NK + it] = wcol;
                sp[it] = wrow; sd[it] = wcol;
            }
            if (lane == wcol) L[wrow * 65 + wcol] = -INFINITY;
            double r0 = L[(2 * lane) * 65 + wcol];
            double r1 = L[(2 * lane + 1) * 65 + wcol];
            double rm; int ri;
            if (r1 > r0) { rm = r1; ri = (2 * lane + 1) * 64 + wcol; }
            else         { rm = r0; ri = (2 * lane) * 64 + wcol; }
            #pragma unroll
            for (int off = 1; off <= 32; off <<= 1) {
                double m2 = __shfl_xor(rm, off, 64);
                int    i2 = __shfl_xor(ri, off, 64);
                if (m2 > rm || (m2 == rm && i2 < ri)) { rm = m2; ri = i2; }
            }
            if (lane == wcol) { mv = rm; mi = ri; }
        }
    }
    __syncthreads();

    for (int i = t; i < NK * NDEPTH; i += 256) {
        int k = i >> 4, j = i & 15;
        hist_out[(b * NK + k) * NDEPTH + j] = (j == tstep) ? (unsigned char)sd[k]
                                            : hist_in[(b * NK + sp[k]) * NDEPTH + j];
    }
}

// ---------------- K3: f64 MFMA RNN step. new_states = tanh(states[parent]@W_hh + b_hh + emb[dec])
// RETILED: grid (256, 4), 256 threads = 4 waves. Block 128 rows (one full batch) x 128 cols.
// Wave (wm,wn) owns 64x64 = 4x4 tiles of 16x16 -> 16 indep accumulators, 64 MFMA/chunk/wave.
// 1024 blocks = 256 CU x 4 resident -> single dispatch round, zero tail.
// stT[16][131]: x131 odd stride reproduces the measured-conflict-free [16][67] bank pattern.
__global__ void __launch_bounds__(256, 4)
k_rnn(const float* __restrict__ states_in,
      const float* __restrict__ Whh,   // [H][H] f32 row-major
      const float* __restrict__ bhh,
      const float* __restrict__ emb,   // [D][H]
      const int* __restrict__ parent, const int* __restrict__ decs,
      float* __restrict__ states_out)
{
    __shared__ double wt[16][128];   // [kk][col] 16384 B
    __shared__ double stT[16][131];  // [kk][r]   16768 B
    __shared__ int sp[128], sd[128];

    const int b    = blockIdx.x;          // batch
    const int rowb = b * 128;
    const int colb = blockIdx.y * 128;
    const int t    = threadIdx.x;
    const int lane = t & 63;
    const int li   = lane & 15;
    const int kq   = lane >> 4;     // 0..3
    const int wv   = t >> 6;
    const int wm   = wv >> 1;       // row-half (0,1)
    const int wn   = wv & 1;        // col-half (0,1)

    if (t < 128) { sp[t] = parent[rowb + t]; sd[t] = decs[rowb + t]; }
    __syncthreads();

    // staging coordinates (constant per thread)
    const int wrow = t >> 6, wcp = t & 63;    // W: row = j*4 + wrow, j=0..3
    const int sr   = t >> 3, scp = t & 7;     // S: r = j*32 + sr, j=0..3
    int srow[4];
    #pragma unroll
    for (int j = 0; j < 4; ++j) srow[j] = b * NK + sp[j * 32 + sr];

    d4 acc[4][4];
    #pragma unroll
    for (int i = 0; i < 4; ++i)
        #pragma unroll
        for (int j = 0; j < 4; ++j) { acc[i][j][0]=0.0; acc[i][j][1]=0.0; acc[i][j][2]=0.0; acc[i][j][3]=0.0; }

    for (int kc = 0; kc < NH; kc += 16) {
        // W tile: 1024 double2 from f32 Whh, linear b128 writes
        #pragma unroll
        for (int j = 0; j < 4; ++j) {
            float2 v = *(const float2*)&Whh[(size_t)(kc + j * 4 + wrow) * NH + colb + 2 * wcp];
            double2 d; d.x = (double)v.x; d.y = (double)v.y;
            *(double2*)&wt[j * 4 + wrow][2 * wcp] = d;
        }
        // S tile (gathered, transposed): stT[kk][r] = S[parent[r]][kc+kk]
        #pragma unroll
        for (int j = 0; j < 4; ++j) {
            int r = j * 32 + sr;
            float2 v = *(const float2*)&states_in[(size_t)srow[j] * NH + kc + 2 * scp];
            stT[2 * scp][r]     = (double)v.x;
            stT[2 * scp + 1][r] = (double)v.y;
        }
        __syncthreads();

        #pragma unroll
        for (int ks = 0; ks < 4; ++ks) {
            int kk = 4 * ks + kq;
            double a0 = stT[kk][wm * 64 +      li];
            double a1 = stT[kk][wm * 64 + 16 + li];
            double a2 = stT[kk][wm * 64 + 32 + li];
            double a3 = stT[kk][wm * 64 + 48 + li];
            double b0 = wt[kk][wn * 64 +      li];
            double b1 = wt[kk][wn * 64 + 16 + li];
            double b2 = wt[kk][wn * 64 + 32 + li];
            double b3 = wt[kk][wn * 64 + 48 + li];
            acc[0][0] = __builtin_amdgcn_mfma_f64_16x16x4f64(a0, b0, acc[0][0], 0, 0, 0);
            acc[0][1] = __builtin_amdgcn_mfma_f64_16x16x4f64(a0, b1, acc[0][1], 0, 0, 0);
            acc[0][2] = __builtin_amdgcn_mfma_f64_16x16x4f64(a0, b2, acc[0][2], 0, 0, 0);
            acc[0][3] = __builtin_amdgcn_mfma_f64_16x16x4f64(a0, b3, acc[0][3], 0, 0, 0);
            acc[1][0] = __builtin_amdgcn_mfma_f64_16x16x4f64(a1, b0, acc[1][0], 0, 0, 0);
            acc[1][1] = __builtin_amdgcn_mfma_f64_16x16x4f64(a1, b1, acc[1][1], 0, 0, 0);
            acc[1][2] = __builtin_amdgcn_mfma_f64_16x16x4f64(a1, b2, acc[1][2], 0, 0, 0);
            acc[1][3] = __builtin_amdgcn_mfma_f64_16x16x4f64(a1, b3, acc[1][3], 0, 0, 0);
            acc[2][0] = __builtin_amdgcn_mfma_f64_16x16x4f64(a2, b0, acc[2][0], 0, 0, 0);
            acc[2][1] = __builtin_amdgcn_mfma_f64_16x16x4f64(a2, b1, acc[2][1], 0, 0, 0);
            acc[2][2] = __builtin_amdgcn_mfma_f64_16x16x4f64(a2, b2, acc[2][2], 0, 0, 0);
            acc[2][3] = __builtin_amdgcn_mfma_f64_16x16x4f64(a2, b3, acc[2][3], 0, 0, 0);
            acc[3][0] = __builtin_amdgcn_mfma_f64_16x16x4f64(a3, b0, acc[3][0], 0, 0, 0);
            acc[3][1] = __builtin_amdgcn_mfma_f64_16x16x4f64(a3, b1, acc[3][1], 0, 0, 0);
            acc[3][2] = __builtin_amdgcn_mfma_f64_16x16x4f64(a3, b2, acc[3][2], 0, 0, 0);
            acc[3][3] = __builtin_amdgcn_mfma_f64_16x16x4f64(a3, b3, acc[3][3], 0, 0, 0);
        }
        __syncthreads();
    }

    // epilogue: D[i][j]: j = lane&15, i = (lane>>4) + 4n (verified L1 layout)
    #pragma unroll
    for (int ct = 0; ct < 4; ++ct) {
        int col = colb + wn * 64 + ct * 16 + li;
        double bb = (double)bhh[col];
        #pragma unroll
        for (int rt = 0; rt < 4; ++rt) {
            #pragma unroll
            for (int n = 0; n < 4; ++n) {
                int rL = wm * 64 + rt * 16 + kq + 4 * n;
                double e = (double)emb[(size_t)sd[rL] * NH + col];
                double z = acc[rt][ct][n] + bb + e;
                states_out[(size_t)(rowb + rL) * NH + col] = (float)tanh(z);
            }
        }
    }
}

// ---------------- finalize: d_out = [hist as float (524288), scores as float (32768)]
__global__ void k_final(const unsigned char* __restrict__ hist,
                        const double* __restrict__ scores,
                        float* __restrict__ out)
{
    int i = blockIdx.x * 256 + threadIdx.x;
    const int nh = BKROWS * NDEPTH;      // 524288
    if (i < nh) out[i] = (float)hist[i];
    else if (i < nh + BKROWS) out[i] = (float)scores[i - nh];
}

extern "C" void kernel_launch(void* const* d_in, const int* in_sizes, int n_in,
                              void* d_out, int out_size, void* d_ws, size_t ws_size,
                              hipStream_t stream) {
    // inputs: env(unused), root_state, W_logits, b_logits, W_hh, b_hh, emb, beams(=128)
    const float* root = (const float*)d_in[1];
    const float* Wl   = (const float*)d_in[2];
    const float* bl   = (const float*)d_in[3];
    const float* Whh  = (const float*)d_in[4];
    const float* bhh  = (const float*)d_in[5];
    const float* emb  = (const float*)d_in[6];

    char* ws = (char*)d_ws;
    double* cand         = (double*)(ws + 0);             // 16,777,216
    double* scores       = (double*)(ws + 16777216);      //    262,144
    float*  sA           = (float*)(ws + 17039360);       // 67,108,864
    float*  sB           = (float*)(ws + 84148224);       // 67,108,864
    int*    parent       = (int*)(ws + 151257088);        //    131,072
    int*    decs         = (int*)(ws + 151388160);        //    131,072
    unsigned char* hA    = (unsigned char*)(ws + 151519232); // 524,288
    unsigned char* hB    = (unsigned char*)(ws + 152043520); // 524,288
    // total 152,567,808 bytes (<= proven 155,713,536)

    k_init<<<65536, 256, 0, stream>>>(root, sA, scores, hA);

    float* scur = sA; float* snxt = sB;
    unsigned char* hcur = hA; unsigned char* hnxt = hB;
    for (int t = 0; t < NDEPTH; ++t) {
        k_logits<<<512, 256, 0, stream>>>(scur, Wl, bl, scores, cand);
        k_topk<<<256, 256, 67584, stream>>>(cand, scores, parent, decs, hcur, hnxt, t);
        k_rnn<<<dim3(256, 4), 256, 0, stream>>>(scur, Whh, bhh, emb, parent, decs, snxt);
        { float* tmp = scur; scur = snxt; snxt = tmp; }
        { unsigned char* tmp = hcur; hcur = hnxt; hnxt = tmp; }
    }

    k_final<<<2176, 256, 0, stream>>>(hcur, scores, (float*)d_out);
}

// Round 12
// 9447.071 us; speedup vs baseline: 3.8841x; 3.8841x over previous
//
#include <hip/hip_runtime.h>
#include <hip/hip_bf16.h>
#include <math.h>

// Problem dims: B=256, K(beams)=128, H=512, D=64, DEPTH=16
#define NB    256
#define NK    128
#define NH    512
#define ND    64
#define NDEPTH 16
#define BKROWS (NB*NK)          // 32768
#define TEMPD 20.0

typedef double d4 __attribute__((ext_vector_type(4)));

// ---------------- init
__global__ void k_init(const float* __restrict__ root, float* __restrict__ states,
                       double* __restrict__ scores, unsigned char* __restrict__ hist) {
    int idx = blockIdx.x * 256 + threadIdx.x;          // 0 .. 16,777,215
    states[idx] = root[idx & (NH - 1)];
    if (idx < BKROWS) scores[idx] = ((idx & (NK - 1)) == 0) ? 0.0 : -1e9;
    if (idx < BKROWS * NDEPTH) hist[idx] = 0;
}

// ---------------- K1: f64 MFMA logits GEMM + log-softmax + cand = score + logp
// grid 512, 256 threads = 4 waves. Block 64 rows x 64 cols; wave wv: rows wv*16..+15.
// DOUBLE-BUFFERED: load(next)->regs, MFMA(cur), write(next->buf^1), one barrier/chunk.
__global__ void __launch_bounds__(256, 4)
k_logits(const float* __restrict__ states,
         const float* __restrict__ Wl,      // [H][D] f32 row-major
         const float* __restrict__ bl,      // [D]
         const double* __restrict__ scores, // [B*K]
         double* __restrict__ cand)         // [B*K][D]
{
    __shared__ double wl[2][16][64];    // [buf][kk][col] -- B-reads stride-1
    __shared__ double stT[2][16][67];   // [buf][kk][r]   -- A-reads stride-1
    const int rowb = blockIdx.x * 64;
    const int t    = threadIdx.x;
    const int lane = t & 63;
    const int wv   = t >> 6;
    const int li   = lane & 15;
    const int kq   = lane >> 4;

    // staging coordinates (constant per thread)
    const int wrow = t >> 5, wcp = t & 31;   // W rows wrow, 8+wrow
    const int sr0 = t >> 3, scp = t & 7;     // S rows sr0, 32+sr0

    float2 wreg[2], sreg[2];
    #define LOGITS_LOAD(kc_) do {                                                            \
        wreg[0] = *(const float2*)&Wl[(size_t)((kc_) + wrow) * ND + 2 * wcp];                \
        wreg[1] = *(const float2*)&Wl[(size_t)((kc_) + 8 + wrow) * ND + 2 * wcp];            \
        sreg[0] = *(const float2*)&states[(size_t)(rowb + sr0) * NH + (kc_) + 2 * scp];      \
        sreg[1] = *(const float2*)&states[(size_t)(rowb + 32 + sr0) * NH + (kc_) + 2 * scp]; \
    } while (0)
    #define LOGITS_WRITE(bf) do {                                                            \
        double2 d0; d0.x = (double)wreg[0].x; d0.y = (double)wreg[0].y;                      \
        *(double2*)&wl[bf][wrow][2 * wcp] = d0;                                              \
        double2 d1; d1.x = (double)wreg[1].x; d1.y = (double)wreg[1].y;                      \
        *(double2*)&wl[bf][8 + wrow][2 * wcp] = d1;                                          \
        stT[bf][2 * scp][sr0]          = (double)sreg[0].x;                                  \
        stT[bf][2 * scp + 1][sr0]      = (double)sreg[0].y;                                  \
        stT[bf][2 * scp][32 + sr0]     = (double)sreg[1].x;                                  \
        stT[bf][2 * scp + 1][32 + sr0] = (double)sreg[1].y;                                  \
    } while (0)

    d4 acc[4];
    #pragma unroll
    for (int c = 0; c < 4; ++c) { acc[c][0]=0.0; acc[c][1]=0.0; acc[c][2]=0.0; acc[c][3]=0.0; }

    LOGITS_LOAD(0); LOGITS_WRITE(0);
    __syncthreads();

    int cur = 0;
    for (int kc = 0; kc < NH; kc += 16) {
        const bool more = (kc + 16) < NH;
        if (more) LOGITS_LOAD(kc + 16);     // loads issue; latency hides under MFMAs

        #pragma unroll
        for (int ks = 0; ks < 4; ++ks) {
            int kk = 4 * ks + kq;
            double a  = stT[cur][kk][wv * 16 + li];
            double b0 = wl[cur][kk][     li];
            double b1 = wl[cur][kk][16 + li];
            double b2 = wl[cur][kk][32 + li];
            double b3 = wl[cur][kk][48 + li];
            acc[0] = __builtin_amdgcn_mfma_f64_16x16x4f64(a, b0, acc[0], 0, 0, 0);
            acc[1] = __builtin_amdgcn_mfma_f64_16x16x4f64(a, b1, acc[1], 0, 0, 0);
            acc[2] = __builtin_amdgcn_mfma_f64_16x16x4f64(a, b2, acc[2], 0, 0, 0);
            acc[3] = __builtin_amdgcn_mfma_f64_16x16x4f64(a, b3, acc[3], 0, 0, 0);
        }
        if (more) LOGITS_WRITE(cur ^ 1);    // other buffer: no pre-write barrier needed
        __syncthreads();
        cur ^= 1;
    }

    const double bd0 = (double)bl[li];
    const double bd1 = (double)bl[16 + li];
    const double bd2 = (double)bl[32 + li];
    const double bd3 = (double)bl[48 + li];
    #pragma unroll
    for (int n = 0; n < 4; ++n) {
        int row = rowb + wv * 16 + kq + 4 * n;
        double x0 = (acc[0][n] + bd0) / TEMPD;
        double x1 = (acc[1][n] + bd1) / TEMPD;
        double x2 = (acc[2][n] + bd2) / TEMPD;
        double x3 = (acc[3][n] + bd3) / TEMPD;
        double m = fmax(fmax(x0, x1), fmax(x2, x3));
        #pragma unroll
        for (int off = 1; off <= 8; off <<= 1) m = fmax(m, __shfl_xor(m, off, 64));
        double e = exp(x0 - m) + exp(x1 - m) + exp(x2 - m) + exp(x3 - m);
        #pragma unroll
        for (int off = 1; off <= 8; off <<= 1) e += __shfl_xor(e, off, 64);
        double ls = log(e);
        double sc = scores[row];
        cand[(size_t)row * ND +      li] = sc + x0 - m - ls;
        cand[(size_t)row * ND + 16 + li] = sc + x1 - m - ls;
        cand[(size_t)row * ND + 32 + li] = sc + x2 - m - ls;
        cand[(size_t)row * ND + 48 + li] = sc + x3 - m - ls;
    }
}

// ---------------- K2: per-batch top-128 of 8192 (value desc, index asc) + hist gather
// Single-wave selection from LDS; zero barriers inside the 128-iteration loop.
__global__ void __launch_bounds__(256)
k_topk(const double* __restrict__ cand,    // [B][8192]
       double* __restrict__ scores,
       int* __restrict__ parent, int* __restrict__ decs,
       const unsigned char* __restrict__ hist_in,
       unsigned char* __restrict__ hist_out,
       int tstep)
{
    extern __shared__ double smem[];
    double* L  = smem;                       // [128][65] flattened
    int*    sp = (int*)(smem + 128 * 65);    // [128]
    int*    sd = sp + NK;                    // [128]

    const int b = blockIdx.x;
    const int t = threadIdx.x;
    const double* cb = cand + (size_t)b * (NK * ND);

    #pragma unroll
    for (int j = 0; j < 32; ++j) {
        int i = j * 256 + t;
        L[(i >> 6) * 65 + (i & 63)] = cb[i];
    }
    __syncthreads();

    if (t < 64) {                            // wave 0 only; wave-synchronous
        const int lane = t;
        double mv = L[lane]; int mi = lane;
        for (int i = 1; i < 128; ++i) {
            double v = L[i * 65 + lane];
            if (v > mv) { mv = v; mi = i * 64 + lane; }
        }
        for (int it = 0; it < NK; ++it) {
            double m = mv; int idx = mi;
            #pragma unroll
            for (int off = 1; off <= 32; off <<= 1) {
                double m2 = __shfl_xor(m, off, 64);
                int    i2 = __shfl_xor(idx, off, 64);
                if (m2 > m || (m2 == m && i2 < idx)) { m = m2; idx = i2; }
            }
            const int wrow = idx >> 6, wcol = idx & 63;
            if (lane == 0) {
                scores[b * NK + it] = m;
                parent[b * NK + it] = wrow;
                decs  [b * NK + it] = wcol;
                sp[it] = wrow; sd[it] = wcol;
            }
            if (lane == wcol) L[wrow * 65 + wcol] = -INFINITY;
            double r0 = L[(2 * lane) * 65 + wcol];
            double r1 = L[(2 * lane + 1) * 65 + wcol];
            double rm; int ri;
            if (r1 > r0) { rm = r1; ri = (2 * lane + 1) * 64 + wcol; }
            else         { rm = r0; ri = (2 * lane) * 64 + wcol; }
            #pragma unroll
            for (int off = 1; off <= 32; off <<= 1) {
                double m2 = __shfl_xor(rm, off, 64);
                int    i2 = __shfl_xor(ri, off, 64);
                if (m2 > rm || (m2 == rm && i2 < ri)) { rm = m2; ri = i2; }
            }
            if (lane == wcol) { mv = rm; mi = ri; }
        }
    }
    __syncthreads();

    for (int i = t; i < NK * NDEPTH; i += 256) {
        int k = i >> 4, j = i & 15;
        hist_out[(b * NK + k) * NDEPTH + j] = (j == tstep) ? (unsigned char)sd[k]
                                            : hist_in[(b * NK + sp[k]) * NDEPTH + j];
    }
}

// ---------------- K3: f64 MFMA RNN step. new_states = tanh(states[parent]@W_hh + b_hh + emb[dec])
// grid (512, 4), 256 threads = 4 waves. Block 64 rows x 128 cols; wave (wm,wn): 32x64.
// DOUBLE-BUFFERED (2-phase template): load(next)->regs, MFMA(cur), write(next->buf^1),
// single barrier per chunk. wt: B-reads stride-1; stT: A-reads stride-1 (conflict-free, r9).
__global__ void __launch_bounds__(256, 4)
k_rnn(const float* __restrict__ states_in,
      const float* __restrict__ Whh,   // [H][H] f32 row-major
      const float* __restrict__ bhh,
      const float* __restrict__ emb,   // [D][H]
      const int* __restrict__ parent, const int* __restrict__ decs,
      float* __restrict__ states_out)
{
    __shared__ double wt[2][16][128];   // [buf][kk][col] 32768 B
    __shared__ double stT[2][16][67];   // [buf][kk][r]   17152 B
    __shared__ int sp[64], sd[64];

    const int rowb = blockIdx.x * 64;
    const int cbk  = blockIdx.y;
    const int colb = cbk * 128;
    const int t    = threadIdx.x;
    const int lane = t & 63;
    const int li   = lane & 15;
    const int kq   = lane >> 4;     // 0..3
    const int wv   = t >> 6;
    const int wm   = wv >> 1;       // row-group (0,1)
    const int wn   = wv & 1;        // col-group (0,1)

    if (t < 64) { sp[t] = parent[rowb + t]; sd[t] = decs[rowb + t]; }
    __syncthreads();

    // staging coordinates (constant per thread)
    const int wrow = t >> 6, wcp = t & 63;    // W: row = j*4 + wrow, j=0..3
    const int sr0 = t >> 3, scp = t & 7;      // S: rows sr0, 32+sr0
    int srow[2];
    srow[0] = ((rowb + sr0) >> 7) * NK + sp[sr0];
    srow[1] = ((rowb + 32 + sr0) >> 7) * NK + sp[32 + sr0];

    float2 wreg[4], sreg[2];
    #define RNN_LOAD(kc_) do {                                                               \
        wreg[0] = *(const float2*)&Whh[(size_t)((kc_) +      wrow) * NH + colb + 2 * wcp];   \
        wreg[1] = *(const float2*)&Whh[(size_t)((kc_) +  4 + wrow) * NH + colb + 2 * wcp];   \
        wreg[2] = *(const float2*)&Whh[(size_t)((kc_) +  8 + wrow) * NH + colb + 2 * wcp];   \
        wreg[3] = *(const float2*)&Whh[(size_t)((kc_) + 12 + wrow) * NH + colb + 2 * wcp];   \
        sreg[0] = *(const float2*)&states_in[(size_t)srow[0] * NH + (kc_) + 2 * scp];        \
        sreg[1] = *(const float2*)&states_in[(size_t)srow[1] * NH + (kc_) + 2 * scp];        \
    } while (0)
    #define RNN_WRITE(bf) do {                                                               \
        _Pragma("unroll")                                                                    \
        for (int j = 0; j < 4; ++j) {                                                        \
            double2 d; d.x = (double)wreg[j].x; d.y = (double)wreg[j].y;                     \
            *(double2*)&wt[bf][j * 4 + wrow][2 * wcp] = d;                                   \
        }                                                                                    \
        stT[bf][2 * scp][sr0]          = (double)sreg[0].x;                                  \
        stT[bf][2 * scp + 1][sr0]      = (double)sreg[0].y;                                  \
        stT[bf][2 * scp][32 + sr0]     = (double)sreg[1].x;                                  \
        stT[bf][2 * scp + 1][32 + sr0] = (double)sreg[1].y;                                  \
    } while (0)

    d4 acc[2][4];
    #pragma unroll
    for (int i = 0; i < 2; ++i)
        #pragma unroll
        for (int j = 0; j < 4; ++j) { acc[i][j][0]=0.0; acc[i][j][1]=0.0; acc[i][j][2]=0.0; acc[i][j][3]=0.0; }

    RNN_LOAD(0); RNN_WRITE(0);
    __syncthreads();

    int cur = 0;
    for (int kc = 0; kc < NH; kc += 16) {
        const bool more = (kc + 16) < NH;
        if (more) RNN_LOAD(kc + 16);        // loads issue; latency hides under MFMAs

        #pragma unroll
        for (int ks = 0; ks < 4; ++ks) {
            int kk = 4 * ks + kq;
            double a0 = stT[cur][kk][wm * 32 + li];
            double a1 = stT[cur][kk][wm * 32 + 16 + li];
            double b0 = wt[cur][kk][wn * 64 +      li];
            double b1 = wt[cur][kk][wn * 64 + 16 + li];
            double b2 = wt[cur][kk][wn * 64 + 32 + li];
            double b3 = wt[cur][kk][wn * 64 + 48 + li];
            acc[0][0] = __builtin_amdgcn_mfma_f64_16x16x4f64(a0, b0, acc[0][0], 0, 0, 0);
            acc[0][1] = __builtin_amdgcn_mfma_f64_16x16x4f64(a0, b1, acc[0][1], 0, 0, 0);
            acc[0][2] = __builtin_amdgcn_mfma_f64_16x16x4f64(a0, b2, acc[0][2], 0, 0, 0);
            acc[0][3] = __builtin_amdgcn_mfma_f64_16x16x4f64(a0, b3, acc[0][3], 0, 0, 0);
            acc[1][0] = __builtin_amdgcn_mfma_f64_16x16x4f64(a1, b0, acc[1][0], 0, 0, 0);
            acc[1][1] = __builtin_amdgcn_mfma_f64_16x16x4f64(a1, b1, acc[1][1], 0, 0, 0);
            acc[1][2] = __builtin_amdgcn_mfma_f64_16x16x4f64(a1, b2, acc[1][2], 0, 0, 0);
            acc[1][3] = __builtin_amdgcn_mfma_f64_16x16x4f64(a1, b3, acc[1][3], 0, 0, 0);
        }
        if (more) RNN_WRITE(cur ^ 1);       // other buffer: no pre-write barrier needed
        __syncthreads();
        cur ^= 1;
    }

    // epilogue: D[i][j]: j = lane&15, i = (lane>>4) + 4n (verified L1)
    #pragma unroll
    for (int ct = 0; ct < 4; ++ct) {
        int col = colb + wn * 64 + ct * 16 + li;
        double bb = (double)bhh[col];
        #pragma unroll
        for (int rt = 0; rt < 2; ++rt) {
            #pragma unroll
            for (int n = 0; n < 4; ++n) {
                int rL = wm * 32 + rt * 16 + kq + 4 * n;
                double e = (double)emb[(size_t)sd[rL] * NH + col];
                double z = acc[rt][ct][n] + bb + e;
                states_out[(size_t)(rowb + rL) * NH + col] = (float)tanh(z);
            }
        }
    }
}

// ---------------- finalize: d_out = [hist as float (524288), scores as float (32768)]
__global__ void k_final(const unsigned char* __restrict__ hist,
                        const double* __restrict__ scores,
                        float* __restrict__ out)
{
    int i = blockIdx.x * 256 + threadIdx.x;
    const int nh = BKROWS * NDEPTH;      // 524288
    if (i < nh) out[i] = (float)hist[i];
    else if (i < nh + BKROWS) out[i] = (float)scores[i - nh];
}

extern "C" void kernel_launch(void* const* d_in, const int* in_sizes, int n_in,
                              void* d_out, int out_size, void* d_ws, size_t ws_size,
                              hipStream_t stream) {
    // inputs: env(unused), root_state, W_logits, b_logits, W_hh, b_hh, emb, beams(=128)
    const float* root = (const float*)d_in[1];
    const float* Wl   = (const float*)d_in[2];
    const float* bl   = (const float*)d_in[3];
    const float* Whh  = (const float*)d_in[4];
    const float* bhh  = (const float*)d_in[5];
    const float* emb  = (const float*)d_in[6];

    char* ws = (char*)d_ws;
    double* cand         = (double*)(ws + 0);             // 16,777,216
    double* scores       = (double*)(ws + 16777216);      //    262,144
    float*  sA           = (float*)(ws + 17039360);       // 67,108,864
    float*  sB           = (float*)(ws + 84148224);       // 67,108,864
    int*    parent       = (int*)(ws + 151257088);        //    131,072
    int*    decs         = (int*)(ws + 151388160);        //    131,072
    unsigned char* hA    = (unsigned char*)(ws + 151519232); // 524,288
    unsigned char* hB    = (unsigned char*)(ws + 152043520); // 524,288
    // total 152,567,808 bytes (<= proven 155,713,536)

    k_init<<<65536, 256, 0, stream>>>(root, sA, scores, hA);

    float* scur = sA; float* snxt = sB;
    unsigned char* hcur = hA; unsigned char* hnxt = hB;
    for (int t = 0; t < NDEPTH; ++t) {
        k_logits<<<512, 256, 0, stream>>>(scur, Wl, bl, scores, cand);
        k_topk<<<256, 256, 67584, stream>>>(cand, scores, parent, decs, hcur, hnxt, t);
        k_rnn<<<dim3(512, 4), 256, 0, stream>>>(scur, Whh, bhh, emb, parent, decs, snxt);
        { float* tmp = scur; scur = snxt; snxt = tmp; }
        { unsigned char* tmp = hcur; hcur = hnxt; hnxt = tmp; }
    }

    k_final<<<2176, 256, 0, stream>>>(hcur, scores, (float*)d_out);
}

// Round 13
// 8642.377 us; speedup vs baseline: 4.2457x; 1.0931x over previous
//
#include <hip/hip_runtime.h>
#include <hip/hip_bf16.h>
#include <math.h>

// Problem dims: B=256, K(beams)=128, H=512, D=64, DEPTH=16
#define NB    256
#define NK    128
#define NH    512
#define ND    64
#define NDEPTH 16
#define BKROWS (NB*NK)          // 32768
#define TEMPD 20.0

typedef double d4 __attribute__((ext_vector_type(4)));

// ---------------- init
__global__ void k_init(const float* __restrict__ root, float* __restrict__ states,
                       double* __restrict__ scores, unsigned char* __restrict__ hist) {
    int idx = blockIdx.x * 256 + threadIdx.x;          // 0 .. 16,777,215
    states[idx] = root[idx & (NH - 1)];
    if (idx < BKROWS) scores[idx] = ((idx & (NK - 1)) == 0) ? 0.0 : -1e9;
    if (idx < BKROWS * NDEPTH) hist[idx] = 0;
}

// ---------------- K1+K2 fused: logits GEMM (f64 MFMA) + log-softmax + top-128 + hist gather.
// grid 256 (one block per batch), 256 threads = 4 waves. Block: 128 rows x 64 cols.
// Wave wv owns rows wv*32..wv*32+31 (2 row-tiles), acc[2][4].
// GEMM tiles wl/stT ALIAS the topk buffer L (dead after last chunk barrier).
// Layouts (probe-verified): A[i][k] i=lane&15,k=lane>>4; B[k][j] j=lane&15,k=lane>>4;
// D[i][j]: j=lane&15, i=(lane>>4)+4*n.
__global__ void __launch_bounds__(256)
k_ltk(const float* __restrict__ states,
      const float* __restrict__ Wl,      // [H][D] f32 row-major
      const float* __restrict__ bl,      // [D]
      double* __restrict__ scores,       // [B*K] read (old) then written (new)
      int* __restrict__ parent, int* __restrict__ decs,
      const unsigned char* __restrict__ hist_in,
      unsigned char* __restrict__ hist_out,
      int tstep)
{
    extern __shared__ char smem[];
    double* L   = (double*)smem;                 // [128][65] (epilogue/topk phase)
    double* wl  = (double*)smem;                 // [16][64]  GEMM phase (aliases L)
    double* stT = (double*)(smem + 8192);        // [16][131] GEMM phase (aliases L)
    int* sp = (int*)(smem + 66560);              // [128]
    int* sd = sp + NK;                           // [128]
    // dynamic LDS = 66560 + 1024 = 67584 B (proven size)

    const int b    = blockIdx.x;
    const int rowb = b * NK;                     // batch b's 128 beam rows
    const int t    = threadIdx.x;
    const int lane = t & 63;
    const int wv   = t >> 6;
    const int li   = lane & 15;
    const int kq   = lane >> 4;

    const int sr = t >> 3, scp = t & 7;          // S staging: rows j*32+sr

    d4 acc[2][4];
    #pragma unroll
    for (int i = 0; i < 2; ++i)
        #pragma unroll
        for (int c = 0; c < 4; ++c) { acc[i][c][0]=0.0; acc[i][c][1]=0.0; acc[i][c][2]=0.0; acc[i][c][3]=0.0; }

    for (int kc = 0; kc < NH; kc += 16) {
        // W tile: 512 double2 (from f32), linear b128 writes
        #pragma unroll
        for (int j = 0; j < 2; ++j) {
            int idx = j * 256 + t;
            int row = idx >> 5, cp = idx & 31;
            float2 v = *(const float2*)&Wl[(size_t)(kc + row) * ND + 2 * cp];
            double2 d; d.x = (double)v.x; d.y = (double)v.y;
            *(double2*)&wl[row * 64 + 2 * cp] = d;
        }
        // S tile transposed: stT[kk][r] = S[rowb+r][kc+kk], r = 0..127
        #pragma unroll
        for (int j = 0; j < 4; ++j) {
            int r = j * 32 + sr;
            float2 v = *(const float2*)&states[(size_t)(rowb + r) * NH + kc + 2 * scp];
            stT[(2 * scp) * 131 + r]     = (double)v.x;
            stT[(2 * scp + 1) * 131 + r] = (double)v.y;
        }
        __syncthreads();

        #pragma unroll
        for (int ks = 0; ks < 4; ++ks) {
            int kk = 4 * ks + kq;
            double a0 = stT[kk * 131 + wv * 32 +      li];
            double a1 = stT[kk * 131 + wv * 32 + 16 + li];
            double b0 = wl[kk * 64 +      li];
            double b1 = wl[kk * 64 + 16 + li];
            double b2 = wl[kk * 64 + 32 + li];
            double b3 = wl[kk * 64 + 48 + li];
            acc[0][0] = __builtin_amdgcn_mfma_f64_16x16x4f64(a0, b0, acc[0][0], 0, 0, 0);
            acc[0][1] = __builtin_amdgcn_mfma_f64_16x16x4f64(a0, b1, acc[0][1], 0, 0, 0);
            acc[0][2] = __builtin_amdgcn_mfma_f64_16x16x4f64(a0, b2, acc[0][2], 0, 0, 0);
            acc[0][3] = __builtin_amdgcn_mfma_f64_16x16x4f64(a0, b3, acc[0][3], 0, 0, 0);
            acc[1][0] = __builtin_amdgcn_mfma_f64_16x16x4f64(a1, b0, acc[1][0], 0, 0, 0);
            acc[1][1] = __builtin_amdgcn_mfma_f64_16x16x4f64(a1, b1, acc[1][1], 0, 0, 0);
            acc[1][2] = __builtin_amdgcn_mfma_f64_16x16x4f64(a1, b2, acc[1][2], 0, 0, 0);
            acc[1][3] = __builtin_amdgcn_mfma_f64_16x16x4f64(a1, b3, acc[1][3], 0, 0, 0);
        }
        __syncthreads();   // after last chunk: all GEMM LDS reads done -> L may overwrite
    }

    // epilogue: logp + old score -> L[row][col] (the topk staging layout)
    const double bd0 = (double)bl[li];
    const double bd1 = (double)bl[16 + li];
    const double bd2 = (double)bl[32 + li];
    const double bd3 = (double)bl[48 + li];
    #pragma unroll
    for (int rt = 0; rt < 2; ++rt) {
        #pragma unroll
        for (int n = 0; n < 4; ++n) {
            int rl = wv * 32 + rt * 16 + kq + 4 * n;    // local row 0..127
            double x0 = (acc[rt][0][n] + bd0) / TEMPD;
            double x1 = (acc[rt][1][n] + bd1) / TEMPD;
            double x2 = (acc[rt][2][n] + bd2) / TEMPD;
            double x3 = (acc[rt][3][n] + bd3) / TEMPD;
            double m = fmax(fmax(x0, x1), fmax(x2, x3));
            #pragma unroll
            for (int off = 1; off <= 8; off <<= 1) m = fmax(m, __shfl_xor(m, off, 64));
            double e = exp(x0 - m) + exp(x1 - m) + exp(x2 - m) + exp(x3 - m);
            #pragma unroll
            for (int off = 1; off <= 8; off <<= 1) e += __shfl_xor(e, off, 64);
            double ls = log(e);
            double sc = scores[rowb + rl];
            L[rl * 65 +      li] = sc + x0 - m - ls;
            L[rl * 65 + 16 + li] = sc + x1 - m - ls;
            L[rl * 65 + 32 + li] = sc + x2 - m - ls;
            L[rl * 65 + 48 + li] = sc + x3 - m - ls;
        }
    }
    __syncthreads();

    // top-128 selection (value desc, index asc): single wave, zero barriers in loop
    if (t < 64) {
        const int ln = t;
        double mv = L[ln]; int mi = ln;
        for (int i = 1; i < 128; ++i) {
            double v = L[i * 65 + ln];
            if (v > mv) { mv = v; mi = i * 64 + ln; }
        }
        for (int it = 0; it < NK; ++it) {
            double m = mv; int idx = mi;
            #pragma unroll
            for (int off = 1; off <= 32; off <<= 1) {
                double m2 = __shfl_xor(m, off, 64);
                int    i2 = __shfl_xor(idx, off, 64);
                if (m2 > m || (m2 == m && i2 < idx)) { m = m2; idx = i2; }
            }
            const int wrow = idx >> 6, wcol = idx & 63;
            if (ln == 0) {
                scores[b * NK + it] = m;
                parent[b * NK + it] = wrow;
                decs  [b * NK + it] = wcol;
                sp[it] = wrow; sd[it] = wcol;
            }
            if (ln == wcol) L[wrow * 65 + wcol] = -INFINITY;
            double r0 = L[(2 * ln) * 65 + wcol];
            double r1 = L[(2 * ln + 1) * 65 + wcol];
            double rm; int ri;
            if (r1 > r0) { rm = r1; ri = (2 * ln + 1) * 64 + wcol; }
            else         { rm = r0; ri = (2 * ln) * 64 + wcol; }
            #pragma unroll
            for (int off = 1; off <= 32; off <<= 1) {
                double m2 = __shfl_xor(rm, off, 64);
                int    i2 = __shfl_xor(ri, off, 64);
                if (m2 > rm || (m2 == rm && i2 < ri)) { rm = m2; ri = i2; }
            }
            if (ln == wcol) { mv = rm; mi = ri; }
        }
    }
    __syncthreads();

    // hist gather: hist_out[b,k,:] = hist_in[b,sp[k],:]; [:,tstep] = sd[k]
    for (int i = t; i < NK * NDEPTH; i += 256) {
        int k = i >> 4, j = i & 15;
        hist_out[(b * NK + k) * NDEPTH + j] = (j == tstep) ? (unsigned char)sd[k]
                                            : hist_in[(b * NK + sp[k]) * NDEPTH + j];
    }
}

// ---------------- K3: f64 MFMA RNN step (round-9 form -- measured best: 364 us, MfmaUtil 65%).
// grid (512, 4), 256 threads = 4 waves. Block 64 rows x 128 cols; wave (wm,wn): 32x64.
// wt[16][128]: B-reads stride-1; stT[16][67]: A-reads stride-1 (measured conflict-free).
__global__ void __launch_bounds__(256, 4)
k_rnn(const float* __restrict__ states_in,
      const float* __restrict__ Whh,   // [H][H] f32 row-major
      const float* __restrict__ bhh,
      const float* __restrict__ emb,   // [D][H]
      const int* __restrict__ parent, const int* __restrict__ decs,
      float* __restrict__ states_out)
{
    __shared__ double wt[16][128];   // [kk][col]
    __shared__ double stT[16][67];   // [kk][r]
    __shared__ int sp[64], sd[64];

    const int rowb = blockIdx.x * 64;
    const int cbk  = blockIdx.y;
    const int colb = cbk * 128;
    const int t    = threadIdx.x;
    const int lane = t & 63;
    const int li   = lane & 15;
    const int kq   = lane >> 4;     // 0..3
    const int wv   = t >> 6;
    const int wm   = wv >> 1;       // row-group (0,1)
    const int wn   = wv & 1;        // col-group (0,1)

    if (t < 64) { sp[t] = parent[rowb + t]; sd[t] = decs[rowb + t]; }
    __syncthreads();

    int srow[2];
    #pragma unroll
    for (int j = 0; j < 2; ++j) {
        int r = (j * 256 + t) >> 3;
        srow[j] = ((rowb + r) >> 7) * NK + sp[r];
    }

    d4 acc[2][4];
    #pragma unroll
    for (int i = 0; i < 2; ++i)
        #pragma unroll
        for (int j = 0; j < 4; ++j) { acc[i][j][0]=0.0; acc[i][j][1]=0.0; acc[i][j][2]=0.0; acc[i][j][3]=0.0; }

    for (int kc = 0; kc < NH; kc += 16) {
        // W tile: 1024 double2 from f32 Whh, linear b128 writes
        #pragma unroll
        for (int j = 0; j < 4; ++j) {
            int idx = j * 256 + t;
            int row = idx >> 6, cp = idx & 63;
            float2 v = *(const float2*)&Whh[(size_t)(kc + row) * NH + colb + 2 * cp];
            double2 d; d.x = (double)v.x; d.y = (double)v.y;
            *(double2*)&wt[row][2 * cp] = d;
        }
        // S tile (gathered, transposed): stT[kk][r] = S[parent[r]][kc+kk]
        #pragma unroll
        for (int j = 0; j < 2; ++j) {
            int idx = j * 256 + t;
            int r = idx >> 3, cp = idx & 7;
            float2 v = *(const float2*)&states_in[(size_t)srow[j] * NH + kc + 2 * cp];
            stT[2 * cp][r]     = (double)v.x;
            stT[2 * cp + 1][r] = (double)v.y;
        }
        __syncthreads();

        #pragma unroll
        for (int ks = 0; ks < 4; ++ks) {
            int kk = 4 * ks + kq;
            double a0 = stT[kk][wm * 32 + li];
            double a1 = stT[kk][wm * 32 + 16 + li];
            double b0 = wt[kk][wn * 64 +      li];
            double b1 = wt[kk][wn * 64 + 16 + li];
            double b2 = wt[kk][wn * 64 + 32 + li];
            double b3 = wt[kk][wn * 64 + 48 + li];
            acc[0][0] = __builtin_amdgcn_mfma_f64_16x16x4f64(a0, b0, acc[0][0], 0, 0, 0);
            acc[0][1] = __builtin_amdgcn_mfma_f64_16x16x4f64(a0, b1, acc[0][1], 0, 0, 0);
            acc[0][2] = __builtin_amdgcn_mfma_f64_16x16x4f64(a0, b2, acc[0][2], 0, 0, 0);
            acc[0][3] = __builtin_amdgcn_mfma_f64_16x16x4f64(a0, b3, acc[0][3], 0, 0, 0);
            acc[1][0] = __builtin_amdgcn_mfma_f64_16x16x4f64(a1, b0, acc[1][0], 0, 0, 0);
            acc[1][1] = __builtin_amdgcn_mfma_f64_16x16x4f64(a1, b1, acc[1][1], 0, 0, 0);
            acc[1][2] = __builtin_amdgcn_mfma_f64_16x16x4f64(a1, b2, acc[1][2], 0, 0, 0);
            acc[1][3] = __builtin_amdgcn_mfma_f64_16x16x4f64(a1, b3, acc[1][3], 0, 0, 0);
        }
        __syncthreads();
    }

    // epilogue: D[i][j]: j = lane&15, i = (lane>>4) + 4n (verified L1)
    #pragma unroll
    for (int ct = 0; ct < 4; ++ct) {
        int col = colb + wn * 64 + ct * 16 + li;
        double bb = (double)bhh[col];
        #pragma unroll
        for (int rt = 0; rt < 2; ++rt) {
            #pragma unroll
            for (int n = 0; n < 4; ++n) {
                int rL = wm * 32 + rt * 16 + kq + 4 * n;
                double e = (double)emb[(size_t)sd[rL] * NH + col];
                double z = acc[rt][ct][n] + bb + e;
                states_out[(size_t)(rowb + rL) * NH + col] = (float)tanh(z);
            }
        }
    }
}

// ---------------- finalize: d_out = [hist as float (524288), scores as float (32768)]
__global__ void k_final(const unsigned char* __restrict__ hist,
                        const double* __restrict__ scores,
                        float* __restrict__ out)
{
    int i = blockIdx.x * 256 + threadIdx.x;
    const int nh = BKROWS * NDEPTH;      // 524288
    if (i < nh) out[i] = (float)hist[i];
    else if (i < nh + BKROWS) out[i] = (float)scores[i - nh];
}

extern "C" void kernel_launch(void* const* d_in, const int* in_sizes, int n_in,
                              void* d_out, int out_size, void* d_ws, size_t ws_size,
                              hipStream_t stream) {
    // inputs: env(unused), root_state, W_logits, b_logits, W_hh, b_hh, emb, beams(=128)
    const float* root = (const float*)d_in[1];
    const float* Wl   = (const float*)d_in[2];
    const float* bl   = (const float*)d_in[3];
    const float* Whh  = (const float*)d_in[4];
    const float* bhh  = (const float*)d_in[5];
    const float* emb  = (const float*)d_in[6];

    char* ws = (char*)d_ws;
    double* scores       = (double*)(ws + 0);             //    262,144
    float*  sA           = (float*)(ws + 262144);         // 67,108,864
    float*  sB           = (float*)(ws + 67371008);       // 67,108,864
    int*    parent       = (int*)(ws + 134479872);        //    131,072
    int*    decs         = (int*)(ws + 134610944);        //    131,072
    unsigned char* hA    = (unsigned char*)(ws + 134742016); // 524,288
    unsigned char* hB    = (unsigned char*)(ws + 135266304); // 524,288
    // total 135,790,592 bytes (<= proven 155,713,536)

    k_init<<<65536, 256, 0, stream>>>(root, sA, scores, hA);

    float* scur = sA; float* snxt = sB;
    unsigned char* hcur = hA; unsigned char* hnxt = hB;
    for (int t = 0; t < NDEPTH; ++t) {
        k_ltk<<<256, 256, 67584, stream>>>(scur, Wl, bl, scores, parent, decs, hcur, hnxt, t);
        k_rnn<<<dim3(512, 4), 256, 0, stream>>>(scur, Whh, bhh, emb, parent, decs, snxt);
        { float* tmp = scur; scur = snxt; snxt = tmp; }
        { unsigned char* tmp = hcur; hcur = hnxt; hnxt = tmp; }
    }

    k_final<<<2176, 256, 0, stream>>>(hcur, scores, (float*)d_out);
}

// Round 14
// 8435.846 us; speedup vs baseline: 4.3497x; 1.0245x over previous
//
#include <hip/hip_runtime.h>
#include <hip/hip_bf16.h>
#include <math.h>

// Problem dims: B=256, K(beams)=128, H=512, D=64, DEPTH=16
#define NB    256
#define NK    128
#define NH    512
#define ND    64
#define NDEPTH 16
#define BKROWS (NB*NK)          // 32768
#define TEMPD 20.0

typedef double d4 __attribute__((ext_vector_type(4)));

// ---------------- init
__global__ void k_init(const float* __restrict__ root, float* __restrict__ states,
                       double* __restrict__ scores, unsigned char* __restrict__ hist) {
    int idx = blockIdx.x * 256 + threadIdx.x;          // 0 .. 16,777,215
    states[idx] = root[idx & (NH - 1)];
    if (idx < BKROWS) scores[idx] = ((idx & (NK - 1)) == 0) ? 0.0 : -1e9;
    if (idx < BKROWS * NDEPTH) hist[idx] = 0;
}

// ---------------- K1+K2 fused: logits GEMM (f64 MFMA) + log-softmax + top-128 + hist gather.
// grid 256 (one block per batch), 512 threads = 8 waves. Block: 128 rows x 64 cols.
// Wave wv owns rows wv*16..wv*16+15 (round-9 k_logits wave shape), acc[4].
// GEMM tiles wl/stT ALIAS the topk buffer L (dead after last chunk barrier).
// Layouts (probe-verified): A[i][k] i=lane&15,k=lane>>4; B[k][j] j=lane&15,k=lane>>4;
// D[i][j]: j=lane&15, i=(lane>>4)+4*n.
__global__ void __launch_bounds__(512)
k_ltk(const float* __restrict__ states,
      const float* __restrict__ Wl,      // [H][D] f32 row-major
      const float* __restrict__ bl,      // [D]
      double* __restrict__ scores,       // [B*K] read (old) then written (new)
      int* __restrict__ parent, int* __restrict__ decs,
      const unsigned char* __restrict__ hist_in,
      unsigned char* __restrict__ hist_out,
      int tstep)
{
    extern __shared__ char smem[];
    double* L   = (double*)smem;                 // [128][65] (epilogue/topk phase)
    double* wl  = (double*)smem;                 // [16][64]  GEMM phase (aliases L)
    double* stT = (double*)(smem + 8192);        // [16][131] GEMM phase (aliases L)
    int* sp = (int*)(smem + 66560);              // [128]
    int* sd = sp + NK;                           // [128]
    // dynamic LDS = 66560 + 1024 = 67584 B (proven size)

    const int b    = blockIdx.x;
    const int rowb = b * NK;                     // batch b's 128 beam rows
    const int t    = threadIdx.x;
    const int lane = t & 63;
    const int wv   = t >> 6;                     // 0..7
    const int li   = lane & 15;
    const int kq   = lane >> 4;

    // staging coordinates (same element sets as round-13, remapped to 512 threads)
    const int wrow = t >> 5, wcp = t & 31;       // W: 512 double2, one per thread
    const int sr = t >> 3, scp = t & 7;          // S: rows j*64+sr, j=0,1

    d4 acc[4];
    #pragma unroll
    for (int c = 0; c < 4; ++c) { acc[c][0]=0.0; acc[c][1]=0.0; acc[c][2]=0.0; acc[c][3]=0.0; }

    for (int kc = 0; kc < NH; kc += 16) {
        // W tile: 512 double2 (from f32), linear b128 writes, 1/thread
        {
            float2 v = *(const float2*)&Wl[(size_t)(kc + wrow) * ND + 2 * wcp];
            double2 d; d.x = (double)v.x; d.y = (double)v.y;
            *(double2*)&wl[wrow * 64 + 2 * wcp] = d;
        }
        // S tile transposed: stT[kk][r] = S[rowb+r][kc+kk], r = 0..127 (2/thread)
        #pragma unroll
        for (int j = 0; j < 2; ++j) {
            int r = j * 64 + sr;
            float2 v = *(const float2*)&states[(size_t)(rowb + r) * NH + kc + 2 * scp];
            stT[(2 * scp) * 131 + r]     = (double)v.x;
            stT[(2 * scp + 1) * 131 + r] = (double)v.y;
        }
        __syncthreads();

        #pragma unroll
        for (int ks = 0; ks < 4; ++ks) {
            int kk = 4 * ks + kq;
            double a  = stT[kk * 131 + wv * 16 + li];
            double b0 = wl[kk * 64 +      li];
            double b1 = wl[kk * 64 + 16 + li];
            double b2 = wl[kk * 64 + 32 + li];
            double b3 = wl[kk * 64 + 48 + li];
            acc[0] = __builtin_amdgcn_mfma_f64_16x16x4f64(a, b0, acc[0], 0, 0, 0);
            acc[1] = __builtin_amdgcn_mfma_f64_16x16x4f64(a, b1, acc[1], 0, 0, 0);
            acc[2] = __builtin_amdgcn_mfma_f64_16x16x4f64(a, b2, acc[2], 0, 0, 0);
            acc[3] = __builtin_amdgcn_mfma_f64_16x16x4f64(a, b3, acc[3], 0, 0, 0);
        }
        __syncthreads();   // after last chunk: all GEMM LDS reads done -> L may overwrite
    }

    // epilogue: logp + old score -> L[row][col] (the topk staging layout)
    const double bd0 = (double)bl[li];
    const double bd1 = (double)bl[16 + li];
    const double bd2 = (double)bl[32 + li];
    const double bd3 = (double)bl[48 + li];
    #pragma unroll
    for (int n = 0; n < 4; ++n) {
        int rl = wv * 16 + kq + 4 * n;               // local row 0..127
        double x0 = (acc[0][n] + bd0) / TEMPD;
        double x1 = (acc[1][n] + bd1) / TEMPD;
        double x2 = (acc[2][n] + bd2) / TEMPD;
        double x3 = (acc[3][n] + bd3) / TEMPD;
        double m = fmax(fmax(x0, x1), fmax(x2, x3));
        #pragma unroll
        for (int off = 1; off <= 8; off <<= 1) m = fmax(m, __shfl_xor(m, off, 64));
        double e = exp(x0 - m) + exp(x1 - m) + exp(x2 - m) + exp(x3 - m);
        #pragma unroll
        for (int off = 1; off <= 8; off <<= 1) e += __shfl_xor(e, off, 64);
        double ls = log(e);
        double sc = scores[rowb + rl];
        L[rl * 65 +      li] = sc + x0 - m - ls;
        L[rl * 65 + 16 + li] = sc + x1 - m - ls;
        L[rl * 65 + 32 + li] = sc + x2 - m - ls;
        L[rl * 65 + 48 + li] = sc + x3 - m - ls;
    }
    __syncthreads();

    // top-128 selection (value desc, index asc): single wave, zero barriers in loop
    if (t < 64) {
        const int ln = t;
        double mv = L[ln]; int mi = ln;
        for (int i = 1; i < 128; ++i) {
            double v = L[i * 65 + ln];
            if (v > mv) { mv = v; mi = i * 64 + ln; }
        }
        for (int it = 0; it < NK; ++it) {
            double m = mv; int idx = mi;
            #pragma unroll
            for (int off = 1; off <= 32; off <<= 1) {
                double m2 = __shfl_xor(m, off, 64);
                int    i2 = __shfl_xor(idx, off, 64);
                if (m2 > m || (m2 == m && i2 < idx)) { m = m2; idx = i2; }
            }
            const int wrw = idx >> 6, wcol = idx & 63;
            if (ln == 0) {
                scores[b * NK + it] = m;
                parent[b * NK + it] = wrw;
                decs  [b * NK + it] = wcol;
                sp[it] = wrw; sd[it] = wcol;
            }
            if (ln == wcol) L[wrw * 65 + wcol] = -INFINITY;
            double r0 = L[(2 * ln) * 65 + wcol];
            double r1 = L[(2 * ln + 1) * 65 + wcol];
            double rm; int ri;
            if (r1 > r0) { rm = r1; ri = (2 * ln + 1) * 64 + wcol; }
            else         { rm = r0; ri = (2 * ln) * 64 + wcol; }
            #pragma unroll
            for (int off = 1; off <= 32; off <<= 1) {
                double m2 = __shfl_xor(rm, off, 64);
                int    i2 = __shfl_xor(ri, off, 64);
                if (m2 > rm || (m2 == rm && i2 < ri)) { rm = m2; ri = i2; }
            }
            if (ln == wcol) { mv = rm; mi = ri; }
        }
    }
    __syncthreads();

    // hist gather: hist_out[b,k,:] = hist_in[b,sp[k],:]; [:,tstep] = sd[k]
    for (int i = t; i < NK * NDEPTH; i += 512) {
        int k = i >> 4, j = i & 15;
        hist_out[(b * NK + k) * NDEPTH + j] = (j == tstep) ? (unsigned char)sd[k]
                                            : hist_in[(b * NK + sp[k]) * NDEPTH + j];
    }
}

// ---------------- K3: f64 MFMA RNN step (round-9 form -- measured best: 364 us, MfmaUtil 65%).
// grid (512, 4), 256 threads = 4 waves. Block 64 rows x 128 cols; wave (wm,wn): 32x64.
// wt[16][128]: B-reads stride-1; stT[16][67]: A-reads stride-1 (measured conflict-free).
__global__ void __launch_bounds__(256, 4)
k_rnn(const float* __restrict__ states_in,
      const float* __restrict__ Whh,   // [H][H] f32 row-major
      const float* __restrict__ bhh,
      const float* __restrict__ emb,   // [D][H]
      const int* __restrict__ parent, const int* __restrict__ decs,
      float* __restrict__ states_out)
{
    __shared__ double wt[16][128];   // [kk][col]
    __shared__ double stT[16][67];   // [kk][r]
    __shared__ int sp[64], sd[64];

    const int rowb = blockIdx.x * 64;
    const int cbk  = blockIdx.y;
    const int colb = cbk * 128;
    const int t    = threadIdx.x;
    const int lane = t & 63;
    const int li   = lane & 15;
    const int kq   = lane >> 4;     // 0..3
    const int wv   = t >> 6;
    const int wm   = wv >> 1;       // row-group (0,1)
    const int wn   = wv & 1;        // col-group (0,1)

    if (t < 64) { sp[t] = parent[rowb + t]; sd[t] = decs[rowb + t]; }
    __syncthreads();

    int srow[2];
    #pragma unroll
    for (int j = 0; j < 2; ++j) {
        int r = (j * 256 + t) >> 3;
        srow[j] = ((rowb + r) >> 7) * NK + sp[r];
    }

    d4 acc[2][4];
    #pragma unroll
    for (int i = 0; i < 2; ++i)
        #pragma unroll
        for (int j = 0; j < 4; ++j) { acc[i][j][0]=0.0; acc[i][j][1]=0.0; acc[i][j][2]=0.0; acc[i][j][3]=0.0; }

    for (int kc = 0; kc < NH; kc += 16) {
        // W tile: 1024 double2 from f32 Whh, linear b128 writes
        #pragma unroll
        for (int j = 0; j < 4; ++j) {
            int idx = j * 256 + t;
            int row = idx >> 6, cp = idx & 63;
            float2 v = *(const float2*)&Whh[(size_t)(kc + row) * NH + colb + 2 * cp];
            double2 d; d.x = (double)v.x; d.y = (double)v.y;
            *(double2*)&wt[row][2 * cp] = d;
        }
        // S tile (gathered, transposed): stT[kk][r] = S[parent[r]][kc+kk]
        #pragma unroll
        for (int j = 0; j < 2; ++j) {
            int idx = j * 256 + t;
            int r = idx >> 3, cp = idx & 7;
            float2 v = *(const float2*)&states_in[(size_t)srow[j] * NH + kc + 2 * cp];
            stT[2 * cp][r]     = (double)v.x;
            stT[2 * cp + 1][r] = (double)v.y;
        }
        __syncthreads();

        #pragma unroll
        for (int ks = 0; ks < 4; ++ks) {
            int kk = 4 * ks + kq;
            double a0 = stT[kk][wm * 32 + li];
            double a1 = stT[kk][wm * 32 + 16 + li];
            double b0 = wt[kk][wn * 64 +      li];
            double b1 = wt[kk][wn * 64 + 16 + li];
            double b2 = wt[kk][wn * 64 + 32 + li];
            double b3 = wt[kk][wn * 64 + 48 + li];
            acc[0][0] = __builtin_amdgcn_mfma_f64_16x16x4f64(a0, b0, acc[0][0], 0, 0, 0);
            acc[0][1] = __builtin_amdgcn_mfma_f64_16x16x4f64(a0, b1, acc[0][1], 0, 0, 0);
            acc[0][2] = __builtin_amdgcn_mfma_f64_16x16x4f64(a0, b2, acc[0][2], 0, 0, 0);
            acc[0][3] = __builtin_amdgcn_mfma_f64_16x16x4f64(a0, b3, acc[0][3], 0, 0, 0);
            acc[1][0] = __builtin_amdgcn_mfma_f64_16x16x4f64(a1, b0, acc[1][0], 0, 0, 0);
            acc[1][1] = __builtin_amdgcn_mfma_f64_16x16x4f64(a1, b1, acc[1][1], 0, 0, 0);
            acc[1][2] = __builtin_amdgcn_mfma_f64_16x16x4f64(a1, b2, acc[1][2], 0, 0, 0);
            acc[1][3] = __builtin_amdgcn_mfma_f64_16x16x4f64(a1, b3, acc[1][3], 0, 0, 0);
        }
        __syncthreads();
    }

    // epilogue: D[i][j]: j = lane&15, i = (lane>>4) + 4n (verified L1)
    #pragma unroll
    for (int ct = 0; ct < 4; ++ct) {
        int col = colb + wn * 64 + ct * 16 + li;
        double bb = (double)bhh[col];
        #pragma unroll
        for (int rt = 0; rt < 2; ++rt) {
            #pragma unroll
            for (int n = 0; n < 4; ++n) {
                int rL = wm * 32 + rt * 16 + kq + 4 * n;
                double e = (double)emb[(size_t)sd[rL] * NH + col];
                double z = acc[rt][ct][n] + bb + e;
                states_out[(size_t)(rowb + rL) * NH + col] = (float)tanh(z);
            }
        }
    }
}

// ---------------- finalize: d_out = [hist as float (524288), scores as float (32768)]
__global__ void k_final(const unsigned char* __restrict__ hist,
                        const double* __restrict__ scores,
                        float* __restrict__ out)
{
    int i = blockIdx.x * 256 + threadIdx.x;
    const int nh = BKROWS * NDEPTH;      // 524288
    if (i < nh) out[i] = (float)hist[i];
    else if (i < nh + BKROWS) out[i] = (float)scores[i - nh];
}

extern "C" void kernel_launch(void* const* d_in, const int* in_sizes, int n_in,
                              void* d_out, int out_size, void* d_ws, size_t ws_size,
                              hipStream_t stream) {
    // inputs: env(unused), root_state, W_logits, b_logits, W_hh, b_hh, emb, beams(=128)
    const float* root = (const float*)d_in[1];
    const float* Wl   = (const float*)d_in[2];
    const float* bl   = (const float*)d_in[3];
    const float* Whh  = (const float*)d_in[4];
    const float* bhh  = (const float*)d_in[5];
    const float* emb  = (const float*)d_in[6];

    char* ws = (char*)d_ws;
    double* scores       = (double*)(ws + 0);             //    262,144
    float*  sA           = (float*)(ws + 262144);         // 67,108,864
    float*  sB           = (float*)(ws + 67371008);       // 67,108,864
    int*    parent       = (int*)(ws + 134479872);        //    131,072
    int*    decs         = (int*)(ws + 134610944);        //    131,072
    unsigned char* hA    = (unsigned char*)(ws + 134742016); // 524,288
    unsigned char* hB    = (unsigned char*)(ws + 135266304); // 524,288
    // total 135,790,592 bytes (<= proven 155,713,536)

    k_init<<<65536, 256, 0, stream>>>(root, sA, scores, hA);

    float* scur = sA; float* snxt = sB;
    unsigned char* hcur = hA; unsigned char* hnxt = hB;
    for (int t = 0; t < NDEPTH; ++t) {
        k_ltk<<<256, 512, 67584, stream>>>(scur, Wl, bl, scores, parent, decs, hcur, hnxt, t);
        k_rnn<<<dim3(512, 4), 256, 0, stream>>>(scur, Whh, bhh, emb, parent, decs, snxt);
        { float* tmp = scur; scur = snxt; snxt = tmp; }
        { unsigned char* tmp = hcur; hcur = hnxt; hnxt = tmp; }
    }

    k_final<<<2176, 256, 0, stream>>>(hcur, scores, (float*)d_out);
}